// Round 4
// baseline (258.025 us; speedup 1.0000x reference)
//
#include <hip/hip_runtime.h>
#include <hip/hip_bf16.h>
#include <stdint.h>

#define B_ 4
#define S_ 1024
#define D_ 1024
#define E_ 8
#define DE_ 128
#define SCALE_ 0.03125f   // 1/sqrt(1024)

typedef __attribute__((ext_vector_type(8))) short short8;
typedef __attribute__((ext_vector_type(4))) float f32x4;
typedef unsigned short ushort_t;
typedef unsigned int uint32;

__device__ __forceinline__ ushort_t f2bf(float f) {
    uint32 u = __float_as_uint(f);
    uint32 r = u + 0x7fffu + ((u >> 16) & 1u);   // round-to-nearest-even
    return (ushort_t)(r >> 16);
}

// ---------------------------------------------------------------------------
// Kernel 1: Q,K fp32 [B][S][E*DE] -> bf16 [B][E][S][DE]  (y=0 -> Q, y=1 -> K)
// ---------------------------------------------------------------------------
__global__ __launch_bounds__(256) void qkprep_kernel(
        const float* __restrict__ Q, const float* __restrict__ K,
        ushort_t* __restrict__ Qb, ushort_t* __restrict__ Kb) {
    int i = blockIdx.x * 256 + threadIdx.x;          // float4 units, 1M per tensor
    const float* src = blockIdx.y ? K : Q;
    ushort_t*    dst = blockIdx.y ? Kb : Qb;
    int dc = i & 31;
    int e  = (i >> 5) & 7;
    int s  = (i >> 8) & 1023;
    int b  = i >> 18;
    size_t in_off  = ((size_t)(b * 1024 + s) << 10) + ((size_t)e << 7) + ((size_t)dc << 2);
    size_t out_off = (((size_t)(b * 8 + e) * 1024 + s) << 7) + ((size_t)dc << 2);
    float4 v = *(const float4*)(src + in_off);
    *(ushort4*)(dst + out_off) = make_ushort4(f2bf(v.x), f2bf(v.y), f2bf(v.z), f2bf(v.w));
}

// ---------------------------------------------------------------------------
// Kernel 2: V fp32 [B][S][E*DE] -> bf16 transposed Vt [B][E][DE][S]
// ---------------------------------------------------------------------------
__global__ __launch_bounds__(256) void vtrans_kernel(
        const float* __restrict__ V, ushort_t* __restrict__ Vt) {
    __shared__ ushort_t tile[128][134];
    const int tid = threadIdx.x;
    const int sc = blockIdx.x, e = blockIdx.y, b = blockIdx.z;
    const int s0 = sc * 128;

    const float* vsrc = V + ((size_t)(b * 1024 + s0) << 10) + (e << 7);
    #pragma unroll
    for (int j = 0; j < 16; ++j) {
        int idx = tid + j * 256, r = idx >> 5, c4 = idx & 31;
        float4 v = *(const float4*)(vsrc + ((size_t)r << 10) + (c4 << 2));
        ushort_t* p = &tile[r][c4 << 2];
        p[0] = f2bf(v.x); p[1] = f2bf(v.y); p[2] = f2bf(v.z); p[3] = f2bf(v.w);
    }
    __syncthreads();
    ushort_t* vdst = Vt + (((size_t)(b * 8 + e)) << 17) + s0;
    #pragma unroll
    for (int j = 0; j < 8; ++j) {
        int idx = tid + j * 256, d = idx >> 4, sg = idx & 15;
        union { uint4 q; ushort_t u[8]; } tmp;
        #pragma unroll
        for (int k = 0; k < 8; ++k) tmp.u[k] = tile[sg * 8 + k][d];
        *(uint4*)&vdst[((size_t)d << 10) + (sg << 3)] = tmp.q;
    }
}

// ---------------------------------------------------------------------------
// Kernel 3: per-expert UNNORMALIZED probs + row sums.
//   probs[b][e][s][t] = bf16( exp(scale * (Q_e K_e^T)[s][t]) )   (no max-sub)
//   lsums[b][e][s]    = sum_t exp(...)
// Grid (stile16=64, e=8, b=4); absent experts exit at once (~1024 active
// blocks = 4/CU = 16 waves/CU). Block = 4 waves; wave w owns t in
// [256w,256w+256) x 16 s-rows. No staging LDS; frags straight from global;
// sacc reused per t-tile so the compiler can pipeline loads deeply.
// ONE barrier per block (cross-wave row-sum).
// ---------------------------------------------------------------------------
__global__ __launch_bounds__(256) void attn_pass1(
        const ushort_t* __restrict__ Qb, const ushort_t* __restrict__ Kb,
        const int* __restrict__ em, ushort_t* __restrict__ probs,
        float* __restrict__ lsums) {

    __shared__ float redbuf[4][16];

    const int stile = blockIdx.x, e = blockIdx.y, b = blockIdx.z;
    if (em[e * B_ + b] == 0) return;                 // uniform

    const int tid  = threadIdx.x;
    const int w    = tid >> 6, lane = tid & 63;
    const int quad = lane >> 4, l16 = lane & 15;
    const int s0 = stile * 16;

    const size_t plane = ((size_t)(b * 8 + e)) << 17;    // Qb/Kb (b,e) slice

    // A-frags: 16 Q rows, reused for all 16 t-tiles
    const ushort_t* qbase = Qb + plane + (((size_t)(s0 + l16)) << 7) + quad * 8;
    short8 af[4];
    #pragma unroll
    for (int kk = 0; kk < 4; ++kk) af[kk] = *(const short8*)(qbase + (kk << 5));

    const ushort_t* kbase = Kb + plane + (((size_t)(w * 256 + l16)) << 7) + quad * 8;
    ushort_t* pbase = probs + (((size_t)(b * 8 + e)) << 20) + (((size_t)s0) << 10) + (w << 8);

    float rsum[4] = {0.f, 0.f, 0.f, 0.f};

    #pragma unroll 4
    for (int tt = 0; tt < 16; ++tt) {
        f32x4 sacc = {0.f, 0.f, 0.f, 0.f};
        #pragma unroll
        for (int kk = 0; kk < 4; ++kk) {
            short8 bf = *(const short8*)(kbase + (tt << 11) + (kk << 5));
            sacc = __builtin_amdgcn_mfma_f32_16x16x32_bf16(af[kk], bf, sacc, 0, 0, 0);
        }
        #pragma unroll
        for (int r = 0; r < 4; ++r) {
            float p = __expf(sacc[r] * SCALE_);
            rsum[r] += p;
            pbase[(((size_t)(quad * 4 + r)) << 10) + (tt << 4) + l16] = f2bf(p);
        }
    }

    // row sums: reduce over l16 lanes (cols), then across 4 waves
    #pragma unroll
    for (int off = 1; off < 16; off <<= 1)
        #pragma unroll
        for (int r = 0; r < 4; ++r) rsum[r] += __shfl_xor(rsum[r], off, 64);
    if (l16 == 0) {
        #pragma unroll
        for (int r = 0; r < 4; ++r) redbuf[w][quad * 4 + r] = rsum[r];
    }
    __syncthreads();
    if (tid < 16) {
        float l = redbuf[0][tid] + redbuf[1][tid] + redbuf[2][tid] + redbuf[3][tid];
        lsums[(((size_t)(b * 8 + e)) << 10) + s0 + tid] = l;
    }
}

// ---------------------------------------------------------------------------
// Kernel 4: out[b][s][eo*128+d] = sum_{e in mask} (1/l_e[s]) * (P_e @ V_eo)
// for the 2 top-k output experts. Grid (stile16=64, sel=2, b=4) = 512 blocks.
// e-loop outer (uniform skip of absent experts), t-loop inner; zero LDS;
// per-expert MFMA partial scaled by 1/l_e per row then accumulated.
// d_out pre-zeroed by memset.
// ---------------------------------------------------------------------------
__global__ __launch_bounds__(256) void attn_pass2(
        const ushort_t* __restrict__ Vt, const ushort_t* __restrict__ probs,
        const float* __restrict__ lsums, const int* __restrict__ em,
        const float* __restrict__ route, float* __restrict__ out) {

    const int stile = blockIdx.x;
    const int sel   = blockIdx.y;
    const int b     = blockIdx.z;
    const int s0  = stile * 16;
    const int tid = threadIdx.x;
    const int w = tid >> 6, lane = tid & 63, quad = lane >> 4, l16 = lane & 15;

    // top-2 (uniform; ties -> lower index, matches lax.top_k)
    const float* rp = route + b * 8;
    float v1 = rp[0]; int i1 = 0;
    #pragma unroll
    for (int i = 1; i < 8; ++i) { float v = rp[i]; if (v > v1) { v1 = v; i1 = i; } }
    float v2 = -1e30f; int i2 = 0;
    #pragma unroll
    for (int i = 0; i < 8; ++i) {
        if (i == i1) continue;
        float v = rp[i]; if (v > v2) { v2 = v; i2 = i; }
    }
    const int e_out = sel ? i2 : i1;

    const ushort_t* vbase = Vt + (((size_t)(b * 8 + e_out)) << 17)
                               + (((size_t)(w * 32 + l16)) << 10) + quad * 8;

    f32x4 facc[2];
    facc[0] = (f32x4){0.f, 0.f, 0.f, 0.f};
    facc[1] = (f32x4){0.f, 0.f, 0.f, 0.f};

    #pragma unroll
    for (int e = 0; e < 8; ++e) {
        if (em[e * B_ + b] == 0) continue;          // uniform skip

        const ushort_t* abase = probs + (((size_t)(b * 8 + e)) << 20)
                                      + (((size_t)(s0 + l16)) << 10) + quad * 8;
        f32x4 o0 = {0.f, 0.f, 0.f, 0.f};
        f32x4 o1 = {0.f, 0.f, 0.f, 0.f};
        #pragma unroll 4
        for (int ts = 0; ts < 32; ++ts) {
            short8 A  = *(const short8*)(abase + (ts << 5));
            short8 B0 = *(const short8*)(vbase + (ts << 5));
            short8 B1 = *(const short8*)(vbase + (16 << 10) + (ts << 5));
            o0 = __builtin_amdgcn_mfma_f32_16x16x32_bf16(A, B0, o0, 0, 0, 0);
            o1 = __builtin_amdgcn_mfma_f32_16x16x32_bf16(A, B1, o1, 0, 0, 0);
        }
        float4 lv = *(const float4*)(lsums + (((size_t)(b * 8 + e)) << 10) + s0 + quad * 4);
        float lvv[4] = {lv.x, lv.y, lv.z, lv.w};
        #pragma unroll
        for (int r = 0; r < 4; ++r) {
            float rinv = 1.0f / lvv[r];
            facc[0][r] += o0[r] * rinv;
            facc[1][r] += o1[r] * rinv;
        }
    }

    float* obase = out + (((size_t)(b * 1024 + s0)) << 10) + e_out * 128;
    #pragma unroll
    for (int n = 0; n < 2; ++n)
        #pragma unroll
        for (int r = 0; r < 4; ++r)
            obase[(((size_t)(quad * 4 + r)) << 10) + w * 32 + n * 16 + l16] = facc[n][r];
}

// ---------------------------------------------------------------------------
extern "C" void kernel_launch(void* const* d_in, const int* in_sizes, int n_in,
                              void* d_out, int out_size, void* d_ws, size_t ws_size,
                              hipStream_t stream) {
    const float* Q     = (const float*)d_in[0];
    const float* K     = (const float*)d_in[1];
    const float* V     = (const float*)d_in[2];
    const float* route = (const float*)d_in[3];
    const int*   em    = (const int*)d_in[4];
    float* out = (float*)d_out;

    const size_t NB = (size_t)B_ * E_ * S_ * DE_;   // 4.19M elems (8.4 MB bf16)
    ushort_t* Qb = (ushort_t*)d_ws;
    ushort_t* Kb = Qb + NB;
    ushort_t* Vt = Kb + NB;
    float*    lsums = (float*)(Vt + NB);            // [B][E][S] fp32 (128 KB)
    ushort_t* probs = (ushort_t*)(lsums + (size_t)B_ * E_ * S_);  // [B][E][S][S] bf16 (67 MB)

    hipMemsetAsync(d_out, 0, (size_t)out_size * sizeof(float), stream);
    dim3 gp(4096, 2);
    qkprep_kernel<<<gp, 256, 0, stream>>>(Q, K, Qb, Kb);
    dim3 gv(8, 8, 4);
    vtrans_kernel<<<gv, 256, 0, stream>>>(V, Vt);
    dim3 g1(64, 8, 4);
    attn_pass1<<<g1, 256, 0, stream>>>(Qb, Kb, em, probs, lsums);
    dim3 g2(64, 2, 4);
    attn_pass2<<<g2, 256, 0, stream>>>(Vt, probs, lsums, em, route, out);
}

// Round 5
// 169.474 us; speedup vs baseline: 1.5225x; 1.5225x over previous
//
#include <hip/hip_runtime.h>
#include <hip/hip_bf16.h>
#include <stdint.h>

#define B_ 4
#define S_ 1024
#define D_ 1024
#define E_ 8
#define DE_ 128
#define SCALE_ 0.03125f   // 1/sqrt(1024)

typedef __attribute__((ext_vector_type(8))) short short8;
typedef __attribute__((ext_vector_type(4))) float f32x4;
typedef unsigned short ushort_t;
typedef unsigned int uint32;

__device__ __forceinline__ ushort_t f2bf(float f) {
    uint32 u = __float_as_uint(f);
    uint32 r = u + 0x7fffu + ((u >> 16) & 1u);   // round-to-nearest-even
    return (ushort_t)(r >> 16);
}
__device__ __forceinline__ float bf2f(ushort_t h) {
    return __uint_as_float(((uint32)h) << 16);
}

// ---------------------------------------------------------------------------
// Kernel 1: K fp32 [B][S][E*DE] -> bf16 Kb [B][E][S][DE]
// ---------------------------------------------------------------------------
__global__ __launch_bounds__(256) void kprep_kernel(
        const float* __restrict__ K, ushort_t* __restrict__ Kb) {
    int i = blockIdx.x * 256 + threadIdx.x;          // float4 units
    int dc = i & 31;
    int e  = (i >> 5) & 7;
    int s  = (i >> 8) & 1023;
    int b  = i >> 18;
    size_t in_off  = ((size_t)(b * 1024 + s) << 10) + ((size_t)e << 7) + ((size_t)dc << 2);
    size_t out_off = (((size_t)(b * 8 + e) * 1024 + s) << 7) + ((size_t)dc << 2);
    float4 k = *(const float4*)(K + in_off);
    *(ushort4*)(Kb + out_off) = make_ushort4(f2bf(k.x), f2bf(k.y), f2bf(k.z), f2bf(k.w));
}

// ---------------------------------------------------------------------------
// Kernel 2: V fp32 [B][S][E*DE] -> bf16 transposed Vt [B][E][DE][S]
// ---------------------------------------------------------------------------
__global__ __launch_bounds__(256) void vtrans_kernel(
        const float* __restrict__ V, ushort_t* __restrict__ Vt) {
    __shared__ ushort_t tile[128][134];
    const int tid = threadIdx.x;
    const int sc = blockIdx.x, e = blockIdx.y, b = blockIdx.z;
    const int s0 = sc * 128;

    const float* vsrc = V + ((size_t)(b * 1024 + s0) << 10) + (e << 7);
    #pragma unroll
    for (int j = 0; j < 16; ++j) {
        int idx = tid + j * 256, r = idx >> 5, c4 = idx & 31;
        float4 v = *(const float4*)(vsrc + ((size_t)r << 10) + (c4 << 2));
        ushort_t* p = &tile[r][c4 << 2];
        p[0] = f2bf(v.x); p[1] = f2bf(v.y); p[2] = f2bf(v.z); p[3] = f2bf(v.w);
    }
    __syncthreads();
    ushort_t* vdst = Vt + (((size_t)(b * 8 + e)) << 17) + s0;
    #pragma unroll
    for (int j = 0; j < 8; ++j) {
        int idx = tid + j * 256, d = idx >> 4, sg = idx & 15;
        union { uint4 q; ushort_t u[8]; } tmp;
        #pragma unroll
        for (int k = 0; k < 8; ++k) tmp.u[k] = tile[sg * 8 + k][d];
        *(uint4*)&vdst[((size_t)d << 10) + (sg << 3)] = tmp.q;
    }
}

// ---------------------------------------------------------------------------
// Kernel 3: per-expert UNNORMALIZED probs + row sums.
// Grid (stile16=64, e=8, b=4); absent experts exit. Block = 4 waves; wave w
// owns t in [256w,256w+256). Loads BATCHED 16-at-a-time into register arrays
// so they pipeline (R3 failure: compiler serialized loads at VGPR=32).
// ---------------------------------------------------------------------------
__global__ __launch_bounds__(256) void attn_pass1(
        const float* __restrict__ Q, const ushort_t* __restrict__ Kb,
        const int* __restrict__ em, ushort_t* __restrict__ probs,
        float* __restrict__ lsums) {

    __shared__ float redbuf[4][16];

    const int stile = blockIdx.x, e = blockIdx.y, b = blockIdx.z;
    if (em[e * B_ + b] == 0) return;                 // uniform

    const int tid  = threadIdx.x;
    const int w    = tid >> 6, lane = tid & 63;
    const int quad = lane >> 4, l16 = lane & 15;
    const int s0 = stile * 16;

    const size_t plane = ((size_t)(b * 8 + e)) << 17;    // Kb (b,e) slice

    // A-frags: 16 Q rows fp32 -> bf16 in-reg, reused for all t-tiles
    short8 af[4];
    const float* qbase = Q + ((size_t)(b * 1024 + s0 + l16) << 10) + (e << 7) + quad * 8;
    #pragma unroll
    for (int kk = 0; kk < 4; ++kk) {
        float4 q0 = *(const float4*)(qbase + kk * 32);
        float4 q1 = *(const float4*)(qbase + kk * 32 + 4);
        union { short8 v; ushort_t u[8]; } a;
        a.u[0] = f2bf(q0.x); a.u[1] = f2bf(q0.y); a.u[2] = f2bf(q0.z); a.u[3] = f2bf(q0.w);
        a.u[4] = f2bf(q1.x); a.u[5] = f2bf(q1.y); a.u[6] = f2bf(q1.z); a.u[7] = f2bf(q1.w);
        af[kk] = a.v;
    }

    const ushort_t* kbase = Kb + plane + (((size_t)(w * 256 + l16)) << 7) + quad * 8;
    ushort_t* pbase = probs + (((size_t)(b * 8 + e)) << 20) + (((size_t)s0) << 10) + (w << 8);

    float rsum[4] = {0.f, 0.f, 0.f, 0.f};

    for (int t4 = 0; t4 < 4; ++t4) {
        short8 bf[16];                      // 16 loads issued back-to-back
        #pragma unroll
        for (int j = 0; j < 4; ++j)
            #pragma unroll
            for (int kk = 0; kk < 4; ++kk)
                bf[j * 4 + kk] = *(const short8*)(
                    kbase + (((size_t)(t4 * 4 + j)) << 11) + (kk << 5));

        f32x4 sacc[4];
        #pragma unroll
        for (int j = 0; j < 4; ++j) sacc[j] = (f32x4){0.f, 0.f, 0.f, 0.f};
        #pragma unroll
        for (int j = 0; j < 4; ++j)
            #pragma unroll
            for (int kk = 0; kk < 4; ++kk)
                sacc[j] = __builtin_amdgcn_mfma_f32_16x16x32_bf16(
                    af[kk], bf[j * 4 + kk], sacc[j], 0, 0, 0);

        #pragma unroll
        for (int j = 0; j < 4; ++j)
            #pragma unroll
            for (int r = 0; r < 4; ++r) {
                float p = __expf(sacc[j][r] * SCALE_);
                rsum[r] += p;
                pbase[(((size_t)(quad * 4 + r)) << 10) + ((t4 * 4 + j) << 4) + l16] = f2bf(p);
            }
    }

    #pragma unroll
    for (int off = 1; off < 16; off <<= 1)
        #pragma unroll
        for (int r = 0; r < 4; ++r) rsum[r] += __shfl_xor(rsum[r], off, 64);
    if (l16 == 0) {
        #pragma unroll
        for (int r = 0; r < 4; ++r) redbuf[w][quad * 4 + r] = rsum[r];
    }
    __syncthreads();
    if (tid < 16) {
        float l = redbuf[0][tid] + redbuf[1][tid] + redbuf[2][tid] + redbuf[3][tid];
        lsums[(((size_t)(b * 8 + e)) << 10) + s0 + tid] = l;
    }
}

// ---------------------------------------------------------------------------
// Kernel 4: attnB[b][s][t] = bf16( sum_e mask[e][b] * probs_e[s][t]/l_e[s] )
// Pure streaming: 2048 blocks x 256 threads, one ushort8 per thread.
// ---------------------------------------------------------------------------
__global__ __launch_bounds__(256) void combine_kernel(
        const ushort_t* __restrict__ probs, const float* __restrict__ lsums,
        const int* __restrict__ em, ushort_t* __restrict__ attnB) {
    int idx = blockIdx.x * 256 + threadIdx.x;        // 512K threads
    int t8 = idx & 127;
    int s  = (idx >> 7) & 1023;
    int b  = idx >> 17;                               // uniform per block

    float acc[8] = {0.f, 0.f, 0.f, 0.f, 0.f, 0.f, 0.f, 0.f};
    #pragma unroll
    for (int e = 0; e < 8; ++e) {
        if (em[e * B_ + b] == 0) continue;            // uniform
        const ushort_t* p = probs + (((size_t)(b * 8 + e)) << 20)
                                  + (((size_t)s) << 10) + (t8 << 3);
        uint4 u = *(const uint4*)p;
        float rinv = 1.0f / lsums[(((size_t)(b * 8 + e)) << 10) + s];
        uint32 uu[4] = {u.x, u.y, u.z, u.w};
        #pragma unroll
        for (int k = 0; k < 4; ++k) {
            acc[2 * k]     += bf2f((ushort_t)(uu[k] & 0xffff)) * rinv;
            acc[2 * k + 1] += bf2f((ushort_t)(uu[k] >> 16))    * rinv;
        }
    }
    union { uint4 q; ushort_t u[8]; } o;
    #pragma unroll
    for (int k = 0; k < 8; ++k) o.u[k] = f2bf(acc[k]);
    *(uint4*)(attnB + (((size_t)(b * 1024 + s)) << 10) + (t8 << 3)) = o.q;
}

// ---------------------------------------------------------------------------
// Kernel 5: out[b][s][e*128+d] = attn @ V_e for the 2 top-k experts.
// Grid (64,2,4) = 512 blocks; wave w owns d in [32w,32w+32). Loads batched
// 24-at-a-time (8 ts x {A,B0,B1}). d_out pre-zeroed by memset.
// ---------------------------------------------------------------------------
__global__ __launch_bounds__(256) void attn_pass2(
        const ushort_t* __restrict__ Vt, const ushort_t* __restrict__ attnB,
        const float* __restrict__ route, float* __restrict__ out) {

    const int stile = blockIdx.x;
    const int sel   = blockIdx.y;
    const int b     = blockIdx.z;
    const int s0  = stile * 16;
    const int tid = threadIdx.x;
    const int w = tid >> 6, lane = tid & 63, quad = lane >> 4, l16 = lane & 15;

    // top-2 (uniform; ties -> lower index, matches lax.top_k)
    const float* rp = route + b * 8;
    float v1 = rp[0]; int i1 = 0;
    #pragma unroll
    for (int i = 1; i < 8; ++i) { float v = rp[i]; if (v > v1) { v1 = v; i1 = i; } }
    float v2 = -1e30f; int i2 = 0;
    #pragma unroll
    for (int i = 0; i < 8; ++i) {
        if (i == i1) continue;
        float v = rp[i]; if (v > v2) { v2 = v; i2 = i; }
    }
    const int e = sel ? i2 : i1;

    const ushort_t* abase = attnB + (((size_t)(b * 1024 + s0 + l16)) << 10) + quad * 8;
    const ushort_t* vbase = Vt + (((size_t)(b * 8 + e)) << 17)
                               + (((size_t)(w * 32 + l16)) << 10) + quad * 8;

    f32x4 oacc[2];
    oacc[0] = (f32x4){0.f, 0.f, 0.f, 0.f};
    oacc[1] = (f32x4){0.f, 0.f, 0.f, 0.f};

    for (int tb = 0; tb < 4; ++tb) {
        short8 A[8], B0[8], B1[8];          // 24 loads issued back-to-back
        #pragma unroll
        for (int j = 0; j < 8; ++j) {
            int ts = tb * 8 + j;
            A[j]  = *(const short8*)(abase + (ts << 5));
            B0[j] = *(const short8*)(vbase + (ts << 5));
            B1[j] = *(const short8*)(vbase + (16 << 10) + (ts << 5));
        }
        #pragma unroll
        for (int j = 0; j < 8; ++j) {
            oacc[0] = __builtin_amdgcn_mfma_f32_16x16x32_bf16(A[j], B0[j], oacc[0], 0, 0, 0);
            oacc[1] = __builtin_amdgcn_mfma_f32_16x16x32_bf16(A[j], B1[j], oacc[1], 0, 0, 0);
        }
    }

    float* obase = out + (((size_t)(b * 1024 + s0)) << 10) + e * 128;
    #pragma unroll
    for (int n = 0; n < 2; ++n)
        #pragma unroll
        for (int r = 0; r < 4; ++r)
            obase[(((size_t)(quad * 4 + r)) << 10) + w * 32 + n * 16 + l16] = oacc[n][r];
}

// ---------------------------------------------------------------------------
extern "C" void kernel_launch(void* const* d_in, const int* in_sizes, int n_in,
                              void* d_out, int out_size, void* d_ws, size_t ws_size,
                              hipStream_t stream) {
    const float* Q     = (const float*)d_in[0];
    const float* K     = (const float*)d_in[1];
    const float* V     = (const float*)d_in[2];
    const float* route = (const float*)d_in[3];
    const int*   em    = (const int*)d_in[4];
    float* out = (float*)d_out;

    const size_t NB = (size_t)B_ * E_ * S_ * DE_;     // 4.19M elems
    ushort_t* Kb = (ushort_t*)d_ws;
    ushort_t* Vt = Kb + NB;
    float*    lsums = (float*)(Vt + NB);              // [B][E][S]
    ushort_t* probs = (ushort_t*)(lsums + (size_t)B_ * E_ * S_);  // [B][E][S][S]
    ushort_t* attnB = probs + ((size_t)B_ * E_ * S_ * S_);        // [B][S][S]

    hipMemsetAsync(d_out, 0, (size_t)out_size * sizeof(float), stream);
    kprep_kernel<<<4096, 256, 0, stream>>>(K, Kb);
    dim3 gv(8, 8, 4);
    vtrans_kernel<<<gv, 256, 0, stream>>>(V, Vt);
    dim3 g1(64, 8, 4);
    attn_pass1<<<g1, 256, 0, stream>>>(Q, Kb, em, probs, lsums);
    combine_kernel<<<2048, 256, 0, stream>>>(probs, lsums, em, attnB);
    dim3 g2(64, 2, 4);
    attn_pass2<<<g2, 256, 0, stream>>>(Vt, attnB, route, out);
}